// Round 1
// baseline (1985.080 us; speedup 1.0000x reference)
//
#include <hip/hip_runtime.h>
#include <math.h>

// Problem constants (B,L,DM,H,DH) = (4,2048,768,12,64)
constexpr int B  = 4;
constexpr int L  = 2048;
constexpr int DM = 768;
constexpr int H  = 12;
constexpr int DH = 64;
constexpr int M  = B * L;      // 8192 rows for all GEMMs
constexpr int RS = H * DH;     // 768, row stride of q/k/v in elements

// ---------------------------------------------------------------------------
// Tiled fp32 GEMM with bias: C[M,N] = A[M,K] * W[K,N] + bias[N]
// 64x64 tile per 256-thread block, 4x4 micro-tile per thread, BK=16.
// ---------------------------------------------------------------------------
__global__ __launch_bounds__(256) void gemm_bias(
    const float* __restrict__ A, const float* __restrict__ W,
    const float* __restrict__ bias, float* __restrict__ C,
    int Mdim, int Ndim, int Kdim)
{
    constexpr int BM = 64, BN = 64, BK = 16;
    __shared__ float As[BK][BM + 1];   // stored transposed: As[k][m]
    __shared__ float Ws[BK][BN + 1];

    const int t  = threadIdx.x;
    const int tx = t % 16;            // output column group
    const int ty = t / 16;            // output row group
    const int m0 = blockIdx.x * BM;
    const int n0 = blockIdx.y * BN;

    float acc[4][4] = {};

    for (int k0 = 0; k0 < Kdim; k0 += BK) {
        // Load A tile (64 rows x 16 cols) as float4, store transposed.
        {
            const int e = t * 4;              // 1024 elements total
            const int r = e / BK, c = e % BK; // c in {0,4,8,12}
            const float4 av = *reinterpret_cast<const float4*>(
                &A[(size_t)(m0 + r) * Kdim + k0 + c]);
            As[c + 0][r] = av.x; As[c + 1][r] = av.y;
            As[c + 2][r] = av.z; As[c + 3][r] = av.w;
        }
        // Load W tile (16 rows x 64 cols) as float4.
        {
            const int e  = t * 4;
            const int kk = e / BN, c = e % BN; // c multiple of 4
            const float4 wv = *reinterpret_cast<const float4*>(
                &W[(size_t)(k0 + kk) * Ndim + n0 + c]);
            Ws[kk][c + 0] = wv.x; Ws[kk][c + 1] = wv.y;
            Ws[kk][c + 2] = wv.z; Ws[kk][c + 3] = wv.w;
        }
        __syncthreads();

        #pragma unroll
        for (int kk = 0; kk < BK; ++kk) {
            float a[4], w[4];
            #pragma unroll
            for (int i = 0; i < 4; ++i) a[i] = As[kk][ty * 4 + i];
            #pragma unroll
            for (int j = 0; j < 4; ++j) w[j] = Ws[kk][tx * 4 + j];
            #pragma unroll
            for (int i = 0; i < 4; ++i)
                #pragma unroll
                for (int j = 0; j < 4; ++j)
                    acc[i][j] = fmaf(a[i], w[j], acc[i][j]);
        }
        __syncthreads();
    }

    #pragma unroll
    for (int i = 0; i < 4; ++i) {
        const int row = m0 + ty * 4 + i;
        #pragma unroll
        for (int j = 0; j < 4; ++j) {
            const int col = n0 + tx * 4 + j;
            C[(size_t)row * Ndim + col] = acc[i][j] + bias[col];
        }
    }
}

// ---------------------------------------------------------------------------
// Flash-style attention (no 1/sqrt(d) scale, per the reference).
// Grid: (L/64, H, B). Block: 256 threads.
// Each block: 64 query rows of one (b,h); iterates 64-key tiles with online
// softmax. q/k/v layout: [B,L,H,DH] fp32 (row stride RS=768).
// ---------------------------------------------------------------------------
__global__ __launch_bounds__(256) void attn(
    const float* __restrict__ Q, const float* __restrict__ K,
    const float* __restrict__ V, float* __restrict__ O)
{
    constexpr int BQ = 64, BKV = 64;
    __shared__ float Qs[BQ][DH + 1];
    __shared__ float Ks[BKV][DH + 1];
    __shared__ float Vs[BKV][DH + 1];
    __shared__ float Ps[BQ][BKV + 1];
    __shared__ float m_s[BQ], l_s[BQ], scale_s[BQ];

    const int t  = threadIdx.x;
    const int tx = t % 16;
    const int ty = t / 16;
    const int q0 = blockIdx.x * BQ;
    const int h  = blockIdx.y;
    const int b  = blockIdx.z;
    const size_t base = ((size_t)b * L * H + h) * DH; // element offset of row 0

    // Load Q tile (64x64 fp32) as float4.
    for (int e = t * 4; e < BQ * DH; e += 1024) {
        const int r = e / DH, c = e % DH;
        const float4 v4 = *reinterpret_cast<const float4*>(
            &Q[base + (size_t)(q0 + r) * RS + c]);
        Qs[r][c + 0] = v4.x; Qs[r][c + 1] = v4.y;
        Qs[r][c + 2] = v4.z; Qs[r][c + 3] = v4.w;
    }
    if (t < BQ) { m_s[t] = -INFINITY; l_s[t] = 0.0f; }
    float o[4][4] = {};
    __syncthreads();

    for (int kt = 0; kt < L; kt += BKV) {
        // Load K and V tiles.
        for (int e = t * 4; e < BKV * DH; e += 1024) {
            const int r = e / DH, c = e % DH;
            const float4 kv = *reinterpret_cast<const float4*>(
                &K[base + (size_t)(kt + r) * RS + c]);
            Ks[r][c + 0] = kv.x; Ks[r][c + 1] = kv.y;
            Ks[r][c + 2] = kv.z; Ks[r][c + 3] = kv.w;
            const float4 vv = *reinterpret_cast<const float4*>(
                &V[base + (size_t)(kt + r) * RS + c]);
            Vs[r][c + 0] = vv.x; Vs[r][c + 1] = vv.y;
            Vs[r][c + 2] = vv.z; Vs[r][c + 3] = vv.w;
        }
        __syncthreads();

        // S micro-tile: s[i][j] = dot(Q[ty*4+i], K[tx*4+j])
        float s[4][4] = {};
        for (int d = 0; d < DH; ++d) {
            float a[4], kk[4];
            #pragma unroll
            for (int i = 0; i < 4; ++i) a[i] = Qs[ty * 4 + i][d];
            #pragma unroll
            for (int j = 0; j < 4; ++j) kk[j] = Ks[tx * 4 + j][d];
            #pragma unroll
            for (int i = 0; i < 4; ++i)
                #pragma unroll
                for (int j = 0; j < 4; ++j)
                    s[i][j] = fmaf(a[i], kk[j], s[i][j]);
        }

        // Online softmax per row (16 lanes per row, same wave).
        #pragma unroll
        for (int i = 0; i < 4; ++i) {
            const int r = ty * 4 + i;
            float mx = fmaxf(fmaxf(s[i][0], s[i][1]), fmaxf(s[i][2], s[i][3]));
            #pragma unroll
            for (int off = 1; off < 16; off <<= 1)
                mx = fmaxf(mx, __shfl_xor(mx, off, 64));
            const float m_old = m_s[r];
            const float m_new = fmaxf(m_old, mx);
            float p[4], sum = 0.0f;
            #pragma unroll
            for (int j = 0; j < 4; ++j) {
                p[j] = __expf(s[i][j] - m_new);
                sum += p[j];
            }
            #pragma unroll
            for (int off = 1; off < 16; off <<= 1)
                sum += __shfl_xor(sum, off, 64);
            #pragma unroll
            for (int j = 0; j < 4; ++j) Ps[r][tx * 4 + j] = p[j];
            if (tx == 0) {
                const float sc = __expf(m_old - m_new);
                m_s[r]     = m_new;
                l_s[r]     = l_s[r] * sc + sum;
                scale_s[r] = sc;
            }
        }
        __syncthreads();

        // Rescale accumulator, then O += P * V.
        #pragma unroll
        for (int i = 0; i < 4; ++i) {
            const float sc = scale_s[ty * 4 + i];
            #pragma unroll
            for (int j = 0; j < 4; ++j) o[i][j] *= sc;
        }
        for (int k = 0; k < BKV; ++k) {
            float pr[4], vv[4];
            #pragma unroll
            for (int i = 0; i < 4; ++i) pr[i] = Ps[ty * 4 + i][k];
            #pragma unroll
            for (int j = 0; j < 4; ++j) vv[j] = Vs[k][tx * 4 + j];
            #pragma unroll
            for (int i = 0; i < 4; ++i)
                #pragma unroll
                for (int j = 0; j < 4; ++j)
                    o[i][j] = fmaf(pr[i], vv[j], o[i][j]);
        }
        __syncthreads();
    }

    // Normalize and write out (same [B,L,H,DH] layout -> flat [M, 768]).
    #pragma unroll
    for (int i = 0; i < 4; ++i) {
        const int r = ty * 4 + i;
        const float inv = 1.0f / l_s[r];
        #pragma unroll
        for (int j = 0; j < 4; ++j) {
            O[base + (size_t)(q0 + r) * RS + tx * 4 + j] = o[i][j] * inv;
        }
    }
}

// ---------------------------------------------------------------------------
extern "C" void kernel_launch(void* const* d_in, const int* in_sizes, int n_in,
                              void* d_out, int out_size, void* d_ws, size_t ws_size,
                              hipStream_t stream)
{
    const float* x  = (const float*)d_in[0];
    const float* Wq = (const float*)d_in[1];
    const float* bq = (const float*)d_in[2];
    const float* Wk = (const float*)d_in[3];
    const float* bk = (const float*)d_in[4];
    const float* Wv = (const float*)d_in[5];
    const float* bv = (const float*)d_in[6];
    const float* Wd = (const float*)d_in[7];
    const float* bd = (const float*)d_in[8];
    float* out = (float*)d_out;

    const size_t slab = (size_t)M * DM;  // 6.29M floats = 25 MB
    float* qb = (float*)d_ws;
    float* kb = qb + slab;
    float* vb = kb + slab;
    float* pf = vb + slab;

    const dim3 gg(M / 64, DM / 64);      // (128, 12)
    const dim3 blk(256);

    // QKV projections: Wq/Wk/Wv are [DM,H,DH] = row-major [768,768].
    gemm_bias<<<gg, blk, 0, stream>>>(x, Wq, bq, qb, M, DM, DM);
    gemm_bias<<<gg, blk, 0, stream>>>(x, Wk, bk, kb, M, DM, DM);
    gemm_bias<<<gg, blk, 0, stream>>>(x, Wv, bv, vb, M, DM, DM);

    // Attention.
    const dim3 ga(L / 64, H, B);         // (32, 12, 4)
    attn<<<ga, blk, 0, stream>>>(qb, kb, vb, pf);

    // Output projection: prefinal flat [M, H*DH] @ Wd flat [(H*DH), DM].
    gemm_bias<<<gg, blk, 0, stream>>>(pf, Wd, bd, out, M, DM, DM);
}

// Round 2
// 389.629 us; speedup vs baseline: 5.0948x; 5.0948x over previous
//
#include <hip/hip_runtime.h>
#include <math.h>

// (B,L,DM,H,DH) = (4,2048,768,12,64)
constexpr int B  = 4;
constexpr int L  = 2048;
constexpr int DM = 768;
constexpr int H  = 12;
constexpr int DH = 64;
constexpr int M  = B * L;          // 8192

typedef __attribute__((ext_vector_type(8)))  short          s16x8;
typedef __attribute__((ext_vector_type(4)))  unsigned short u16x4;
typedef __attribute__((ext_vector_type(16))) float          f32x16;
typedef __attribute__((ext_vector_type(4)))  float          f32x4;
typedef unsigned short ushort_t;

__device__ __forceinline__ unsigned short f2bf(float f) {
    unsigned u = __builtin_bit_cast(unsigned, f);
    u = u + 0x7FFFu + ((u >> 16) & 1u);          // RNE
    return (unsigned short)(u >> 16);
}
__device__ __forceinline__ float bf2f(unsigned short h) {
    unsigned u = ((unsigned)h) << 16;
    return __builtin_bit_cast(float, u);
}

#define MFMA32(a, b, c) __builtin_amdgcn_mfma_f32_32x32x16_bf16((a), (b), (c), 0, 0, 0)

// ---------------------------------------------------------------------------
// Prep: split x (fp32) -> hi/lo bf16
// ---------------------------------------------------------------------------
__global__ __launch_bounds__(256) void split_x(
    const float* __restrict__ x, ushort_t* __restrict__ xh,
    ushort_t* __restrict__ xl, int n)
{
    const int i = (blockIdx.x * 256 + threadIdx.x) * 4;
    if (i >= n) return;
    const float4 v = *reinterpret_cast<const float4*>(&x[i]);
    const float vv[4] = {v.x, v.y, v.z, v.w};
    u16x4 hh, ll;
    #pragma unroll
    for (int j = 0; j < 4; ++j) {
        const unsigned short h = f2bf(vv[j]);
        hh[j] = h;
        ll[j] = f2bf(vv[j] - bf2f(h));
    }
    *reinterpret_cast<u16x4*>(&xh[i]) = hh;
    *reinterpret_cast<u16x4*>(&xl[i]) = ll;
}

// ---------------------------------------------------------------------------
// Prep: W [768 x 768] fp32 -> transposed bf16 WT[n][k] (hi, optionally lo)
// ---------------------------------------------------------------------------
template<bool LO>
__global__ __launch_bounds__(256) void splitT_w(
    const float* __restrict__ W, ushort_t* __restrict__ WhT,
    ushort_t* __restrict__ WlT)
{
    const int i = (blockIdx.x * 256 + threadIdx.x) * 4;   // i < 768*768
    const int k = i / 768, n = i % 768;
    const float4 v = *reinterpret_cast<const float4*>(&W[i]);
    const float vv[4] = {v.x, v.y, v.z, v.w};
    #pragma unroll
    for (int j = 0; j < 4; ++j) {
        const unsigned short h = f2bf(vv[j]);
        WhT[(size_t)(n + j) * 768 + k] = h;
        if constexpr (LO)
            WlT[(size_t)(n + j) * 768 + k] = f2bf(vv[j] - bf2f(h));
    }
}

// ---------------------------------------------------------------------------
// MFMA GEMM: C[M,768] = A[M,768] * W[768,768] + bias, via 32x32x16 bf16.
// NT=3: 3-term hi/lo compensated product. Tile 128x64, 4 waves, BK=32.
// EPI 0: write split bf16 (out0=hi, out1=lo)
// EPI 1: write bf16 transposed to vt[b][h][dh][l]
// EPI 2: write fp32
// ---------------------------------------------------------------------------
template<int NT, int EPI>
__global__ __launch_bounds__(256) void gemm_mfma(
    const ushort_t* __restrict__ Ah, const ushort_t* __restrict__ Al,
    const ushort_t* __restrict__ Wh, const ushort_t* __restrict__ Wl,
    const float* __restrict__ bias, void* __restrict__ out0,
    void* __restrict__ out1)
{
    constexpr int KD = 768;
    __shared__ __align__(16) ushort_t Ahs[128][40];
    __shared__ __align__(16) ushort_t Whs[64][40];
    __shared__ __align__(16) ushort_t Als[NT == 3 ? 128 : 1][NT == 3 ? 40 : 8];
    __shared__ __align__(16) ushort_t Wls[NT == 3 ? 64  : 1][NT == 3 ? 40 : 8];

    const int t = threadIdx.x, lane = t & 63, w = t >> 6;
    const int l31 = lane & 31, l5 = lane >> 5;
    const int m0 = blockIdx.x * 128, n0 = blockIdx.y * 64;
    const int ar = t >> 2, ac = (t & 3) * 8;

    f32x16 acc[2] = {};

    for (int k0 = 0; k0 < KD; k0 += 32) {
        #pragma unroll
        for (int p = 0; p < 2; ++p) {
            const int row = ar + p * 64;
            *reinterpret_cast<s16x8*>(&Ahs[row][ac]) =
                *reinterpret_cast<const s16x8*>(&Ah[(size_t)(m0 + row) * KD + k0 + ac]);
            if constexpr (NT == 3)
                *reinterpret_cast<s16x8*>(&Als[row][ac]) =
                    *reinterpret_cast<const s16x8*>(&Al[(size_t)(m0 + row) * KD + k0 + ac]);
        }
        *reinterpret_cast<s16x8*>(&Whs[ar][ac]) =
            *reinterpret_cast<const s16x8*>(&Wh[(size_t)(n0 + ar) * KD + k0 + ac]);
        if constexpr (NT == 3)
            *reinterpret_cast<s16x8*>(&Wls[ar][ac]) =
                *reinterpret_cast<const s16x8*>(&Wl[(size_t)(n0 + ar) * KD + k0 + ac]);
        __syncthreads();

        #pragma unroll
        for (int ks = 0; ks < 2; ++ks) {
            const int koff = ks * 16 + l5 * 8;
            const s16x8 afh = *reinterpret_cast<const s16x8*>(&Ahs[w * 32 + l31][koff]);
            s16x8 afl;
            if constexpr (NT == 3)
                afl = *reinterpret_cast<const s16x8*>(&Als[w * 32 + l31][koff]);
            #pragma unroll
            for (int nt = 0; nt < 2; ++nt) {
                const s16x8 wfh = *reinterpret_cast<const s16x8*>(&Whs[nt * 32 + l31][koff]);
                acc[nt] = MFMA32(afh, wfh, acc[nt]);
                if constexpr (NT == 3) {
                    const s16x8 wfl = *reinterpret_cast<const s16x8*>(&Wls[nt * 32 + l31][koff]);
                    acc[nt] = MFMA32(afh, wfl, acc[nt]);
                    acc[nt] = MFMA32(afl, wfh, acc[nt]);
                }
            }
        }
        __syncthreads();
    }

    const float b0 = bias[n0 + l31], b1 = bias[n0 + 32 + l31];
    #pragma unroll
    for (int nt = 0; nt < 2; ++nt) {
        const int n = n0 + nt * 32 + l31;
        const float bb = nt ? b1 : b0;
        #pragma unroll
        for (int reg = 0; reg < 16; ++reg) {
            const int rowl = (reg & 3) + 8 * (reg >> 2) + 4 * l5;
            const int m = m0 + w * 32 + rowl;
            const float v = acc[nt][reg] + bb;
            if constexpr (EPI == 0) {
                const unsigned short h = f2bf(v);
                ((ushort_t*)out0)[(size_t)m * 768 + n] = h;
                ((ushort_t*)out1)[(size_t)m * 768 + n] = f2bf(v - bf2f(h));
            } else if constexpr (EPI == 1) {
                const int hh = n >> 6, dh = n & 63, bq = m >> 11, lq = m & 2047;
                ((ushort_t*)out0)[((((size_t)bq * H + hh) * DH + dh) << 11) + lq] = f2bf(v);
            } else {
                ((float*)out0)[(size_t)m * 768 + n] = v;
            }
        }
    }
}

// ---------------------------------------------------------------------------
// Flash attention, MFMA 32x32x16, swapped QK^T (S^T = K*Q^T).
// Grid (L/128, H, B); 256 threads = 4 waves; wave owns 32 q rows.
// Q/K hi/lo split (3-term scores), P/V plain bf16.
// ---------------------------------------------------------------------------
__global__ __launch_bounds__(256) void attn_mfma(
    const ushort_t* __restrict__ qh, const ushort_t* __restrict__ ql,
    const ushort_t* __restrict__ kh, const ushort_t* __restrict__ kl,
    const ushort_t* __restrict__ vt, ushort_t* __restrict__ pf)
{
    __shared__ __align__(16) ushort_t Khs[64][72];
    __shared__ __align__(16) ushort_t Kls[64][72];
    __shared__ __align__(16) ushort_t Vts[64][72];
    __shared__ __align__(16) ushort_t Ps[4][32][72];
    __shared__ __align__(16) float scale_s[4][32];
    __shared__ __align__(16) float l_s[4][32];

    const int t = threadIdx.x, lane = t & 63, w = t >> 6;
    const int l31 = lane & 31, l5 = lane >> 5;
    const int qt = blockIdx.x, h = blockIdx.y, b = blockIdx.z;

    // Q fragments in registers (B-operand layout: col=q=l31, k=d)
    const int qrow = qt * 128 + w * 32 + l31;
    const size_t qb = ((size_t)(b * L + qrow)) * 768 + h * 64;
    s16x8 qfh[4], qfl[4];
    #pragma unroll
    for (int ks = 0; ks < 4; ++ks) {
        const int d = ks * 16 + l5 * 8;
        qfh[ks] = *reinterpret_cast<const s16x8*>(&qh[qb + d]);
        qfl[ks] = *reinterpret_cast<const s16x8*>(&ql[qb + d]);
    }

    f32x16 o[2] = {};
    float m_run = -3.0e38f, l_run = 0.0f;
    const int sr = t >> 3, scc = (t & 7) * 8;

    for (int kt = 0; kt < L / 64; ++kt) {
        // stage K hi/lo and V^T tiles
        #pragma unroll
        for (int p = 0; p < 2; ++p) {
            const int row = sr + p * 32;
            const size_t kg = ((size_t)(b * L + kt * 64 + row)) * 768 + h * 64 + scc;
            *reinterpret_cast<s16x8*>(&Khs[row][scc]) =
                *reinterpret_cast<const s16x8*>(&kh[kg]);
            *reinterpret_cast<s16x8*>(&Kls[row][scc]) =
                *reinterpret_cast<const s16x8*>(&kl[kg]);
            const size_t vg = (((size_t)b * H + h) * DH + row) * (size_t)L + kt * 64 + scc;
            *reinterpret_cast<s16x8*>(&Vts[row][scc]) =
                *reinterpret_cast<const s16x8*>(&vt[vg]);
        }
        __syncthreads();

        // S^T = K * Q^T (3-term hi/lo)
        f32x16 st[2] = {};
        #pragma unroll
        for (int mt = 0; mt < 2; ++mt) {
            #pragma unroll
            for (int ks = 0; ks < 4; ++ks) {
                const int koff = ks * 16 + l5 * 8;
                const s16x8 kfh = *reinterpret_cast<const s16x8*>(&Khs[mt * 32 + l31][koff]);
                const s16x8 kfl = *reinterpret_cast<const s16x8*>(&Kls[mt * 32 + l31][koff]);
                st[mt] = MFMA32(kfh, qfh[ks], st[mt]);
                st[mt] = MFMA32(kfl, qfh[ks], st[mt]);
                st[mt] = MFMA32(kfh, qfl[ks], st[mt]);
            }
        }

        // online softmax: lane owns q = l31; xor-32 partner holds other 32 keys
        float pmax = -3.0e38f;
        #pragma unroll
        for (int mt = 0; mt < 2; ++mt)
            #pragma unroll
            for (int e = 0; e < 16; ++e) pmax = fmaxf(pmax, st[mt][e]);
        pmax = fmaxf(pmax, __shfl_xor(pmax, 32));
        const float mnew = fmaxf(m_run, pmax);
        float sum = 0.0f;
        #pragma unroll
        for (int mt = 0; mt < 2; ++mt)
            #pragma unroll
            for (int e = 0; e < 16; ++e) {
                const float ev = __expf(st[mt][e] - mnew);
                st[mt][e] = ev;
                sum += ev;
            }
        sum += __shfl_xor(sum, 32);
        const float sc = __expf(m_run - mnew);
        m_run = mnew;
        l_run = l_run * sc + sum;
        scale_s[w][l31] = sc;

        // write P^T -> Ps[w][q][key] (bf16, packed b64 writes)
        #pragma unroll
        for (int mt = 0; mt < 2; ++mt)
            #pragma unroll
            for (int rg = 0; rg < 4; ++rg) {
                u16x4 pk;
                pk[0] = f2bf(st[mt][rg * 4 + 0]);
                pk[1] = f2bf(st[mt][rg * 4 + 1]);
                pk[2] = f2bf(st[mt][rg * 4 + 2]);
                pk[3] = f2bf(st[mt][rg * 4 + 3]);
                const int key0 = mt * 32 + 8 * rg + 4 * l5;
                *reinterpret_cast<u16x4*>(&Ps[w][l31][key0]) = pk;
            }
        __syncthreads();

        // rescale O accumulators (per output row = q)
        #pragma unroll
        for (int rg = 0; rg < 4; ++rg) {
            const f32x4 sc4 = *reinterpret_cast<const f32x4*>(&scale_s[w][8 * rg + 4 * l5]);
            #pragma unroll
            for (int j = 0; j < 4; ++j) {
                o[0][rg * 4 + j] *= sc4[j];
                o[1][rg * 4 + j] *= sc4[j];
            }
        }

        // O += P * V
        #pragma unroll
        for (int ks = 0; ks < 4; ++ks) {
            const int koff = ks * 16 + l5 * 8;
            const s16x8 pa = *reinterpret_cast<const s16x8*>(&Ps[w][l31][koff]);
            #pragma unroll
            for (int dt = 0; dt < 2; ++dt) {
                const s16x8 vb = *reinterpret_cast<const s16x8*>(&Vts[dt * 32 + l31][koff]);
                o[dt] = MFMA32(pa, vb, o[dt]);
            }
        }
        __syncthreads();
    }

    l_s[w][l31] = l_run;
    __syncthreads();

    const size_t ob = ((size_t)(b * L + qt * 128 + w * 32)) * 768 + h * 64;
    #pragma unroll
    for (int rg = 0; rg < 4; ++rg) {
        const f32x4 lv = *reinterpret_cast<const f32x4*>(&l_s[w][8 * rg + 4 * l5]);
        #pragma unroll
        for (int j = 0; j < 4; ++j) {
            const float inv = 1.0f / lv[j];
            const int rowl = j + 8 * rg + 4 * l5;
            #pragma unroll
            for (int dt = 0; dt < 2; ++dt) {
                pf[ob + (size_t)rowl * 768 + dt * 32 + l31] =
                    f2bf(o[dt][rg * 4 + j] * inv);
            }
        }
    }
}

// ---------------------------------------------------------------------------
extern "C" void kernel_launch(void* const* d_in, const int* in_sizes, int n_in,
                              void* d_out, int out_size, void* d_ws, size_t ws_size,
                              hipStream_t stream)
{
    const float* x  = (const float*)d_in[0];
    const float* Wq = (const float*)d_in[1];
    const float* bq = (const float*)d_in[2];
    const float* Wk = (const float*)d_in[3];
    const float* bk = (const float*)d_in[4];
    const float* Wv = (const float*)d_in[5];
    const float* bv = (const float*)d_in[6];
    const float* Wd = (const float*)d_in[7];
    const float* bd = (const float*)d_in[8];
    float* out = (float*)d_out;

    constexpr size_t S  = (size_t)M * 768;   // activation slab (elements)
    constexpr size_t WS = (size_t)768 * 768; // weight slab (elements)
    ushort_t* p = (ushort_t*)d_ws;
    ushort_t* xh   = p; p += S;
    ushort_t* xl   = p; p += S;
    ushort_t* qhb  = p; p += S;
    ushort_t* qlb  = p; p += S;
    ushort_t* khb  = p; p += S;
    ushort_t* klb  = p; p += S;
    ushort_t* vtb  = p; p += S;
    ushort_t* WqhT = p; p += WS;
    ushort_t* WqlT = p; p += WS;
    ushort_t* WkhT = p; p += WS;
    ushort_t* WklT = p; p += WS;
    ushort_t* WvT  = p; p += WS;
    ushort_t* WdT  = p; p += WS;
    ushort_t* pfb  = xh;                      // xh dead after V projection

    // preps
    split_x<<<dim3((int)(S / 1024)), dim3(256), 0, stream>>>(x, xh, xl, (int)S);
    splitT_w<true ><<<dim3(576), dim3(256), 0, stream>>>(Wq, WqhT, WqlT);
    splitT_w<true ><<<dim3(576), dim3(256), 0, stream>>>(Wk, WkhT, WklT);
    splitT_w<false><<<dim3(576), dim3(256), 0, stream>>>(Wv, WvT, nullptr);
    splitT_w<false><<<dim3(576), dim3(256), 0, stream>>>(Wd, WdT, nullptr);

    const dim3 gg(M / 128, DM / 64);          // (64, 12)
    const dim3 blk(256);

    // Q,K projections (3-term, split output); V projection (plain, transposed out)
    gemm_mfma<3, 0><<<gg, blk, 0, stream>>>(xh, xl, WqhT, WqlT, bq, qhb, qlb);
    gemm_mfma<3, 0><<<gg, blk, 0, stream>>>(xh, xl, WkhT, WklT, bk, khb, klb);
    gemm_mfma<1, 1><<<gg, blk, 0, stream>>>(xh, nullptr, WvT, nullptr, bv, vtb, nullptr);

    // attention
    attn_mfma<<<dim3(L / 128, H, B), blk, 0, stream>>>(qhb, qlb, khb, klb, vtb, pfb);

    // output projection (fp32 out)
    gemm_mfma<1, 2><<<gg, blk, 0, stream>>>(pfb, nullptr, WdT, nullptr, bd, out, nullptr);
}

// Round 7
// 313.061 us; speedup vs baseline: 6.3409x; 1.2446x over previous
//
#include <hip/hip_runtime.h>
#include <math.h>

// (B,L,DM,H,DH) = (4,2048,768,12,64)
constexpr int B  = 4;
constexpr int L  = 2048;
constexpr int DM = 768;
constexpr int H  = 12;
constexpr int DH = 64;
constexpr int M  = B * L;          // 8192
constexpr float LOG2E = 1.4426950408889634f;

typedef __attribute__((ext_vector_type(8)))  _Float16       f16x8;
typedef __attribute__((ext_vector_type(8)))  short          s16x8;
typedef __attribute__((ext_vector_type(4)))  unsigned short u16x4;
typedef __attribute__((ext_vector_type(4)))  unsigned int   u32x4;
typedef __attribute__((ext_vector_type(16))) float          f32x16;
typedef __attribute__((ext_vector_type(4)))  float          f32x4;
typedef unsigned short ushort_t;
typedef unsigned int   uint_t;

#define MFMA16(a, b, c) __builtin_amdgcn_mfma_f32_32x32x16_f16((a), (b), (c), 0, 0, 0)

#if __has_builtin(__builtin_amdgcn_exp2f)
#define EXP2(x) __builtin_amdgcn_exp2f(x)
#else
#define EXP2(x) exp2f(x)
#endif

__device__ __forceinline__ ushort_t h_bits(_Float16 h) {
    return __builtin_bit_cast(ushort_t, h);
}
__device__ __forceinline__ uint_t pkrtz(float a, float b) {
    return __builtin_bit_cast(uint_t, __builtin_amdgcn_cvt_pkrtz(a, b));
}
__device__ __forceinline__ void plswap(uint_t& x, uint_t& y) {
    // v_permlane32_swap_b32 vdst, vsrc: exchanges vdst lanes[32:63] with
    // vsrc lanes[0:31]. After plswap(x,y): x = {x_lo, y_lo}, y = {x_hi, y_hi}.
    asm volatile("v_permlane32_swap_b32 %0, %1" : "+v"(x), "+v"(y));
}

// ---------------------------------------------------------------------------
// Prep: split x (fp32) -> hi/lo f16
// ---------------------------------------------------------------------------
__global__ __launch_bounds__(256) void split_x(
    const float* __restrict__ x, ushort_t* __restrict__ xh,
    ushort_t* __restrict__ xl, int n)
{
    const int i = (blockIdx.x * 256 + threadIdx.x) * 4;
    if (i >= n) return;
    const float4 v = *reinterpret_cast<const float4*>(&x[i]);
    const float vv[4] = {v.x, v.y, v.z, v.w};
    u16x4 hh, ll;
    #pragma unroll
    for (int j = 0; j < 4; ++j) {
        const _Float16 h = (_Float16)vv[j];
        const _Float16 l = (_Float16)(vv[j] - (float)h);
        hh[j] = h_bits(h);
        ll[j] = h_bits(l);
    }
    *reinterpret_cast<u16x4*>(&xh[i]) = hh;
    *reinterpret_cast<u16x4*>(&xl[i]) = ll;
}

// ---------------------------------------------------------------------------
// Prep: W [768 x 768] fp32 -> transposed f16 WT[n][k]
// ---------------------------------------------------------------------------
__global__ __launch_bounds__(256) void h16T_w(
    const float* __restrict__ W, ushort_t* __restrict__ WT)
{
    const int i = (blockIdx.x * 256 + threadIdx.x) * 4;   // i < 768*768
    const int k = i / 768, n = i % 768;
    const float4 v = *reinterpret_cast<const float4*>(&W[i]);
    const float vv[4] = {v.x, v.y, v.z, v.w};
    #pragma unroll
    for (int j = 0; j < 4; ++j)
        WT[(size_t)(n + j) * 768 + k] = h_bits((_Float16)vv[j]);
}

// ---------------------------------------------------------------------------
// MFMA GEMM: C[M,768] = A[M,768]*W[768,768] + bias, f16 32x32x16.
// Tile 128x96, 4 waves (each 32 rows x 96 cols), BK=32, reg-prefetch.
// NT=2: A = hi+lo (2-term).  NT=1: A = hi only.
// EPI 0: split f16 hi/lo -> out0/out1       (Q; scaled by LOG2E if QS)
// EPI 1: f16 transposed  -> vt[b][h][dh][l] (V)
// EPI 2: fp32            -> out0            (final)
// EPI 3: f16 plain       -> out0            (K)
// ---------------------------------------------------------------------------
template<int NT, int EPI, int QS>
__global__ __launch_bounds__(256) void gemm2(
    const ushort_t* __restrict__ Ah, const ushort_t* __restrict__ Al,
    const ushort_t* __restrict__ Wh, const float* __restrict__ bias,
    void* __restrict__ out0, void* __restrict__ out1)
{
    constexpr int KD = 768;
    __shared__ __align__(16) ushort_t Ahs[128][40];
    __shared__ __align__(16) ushort_t Als[NT == 2 ? 128 : 1][NT == 2 ? 40 : 8];
    __shared__ __align__(16) ushort_t Whs[96][40];

    const int t = threadIdx.x, lane = t & 63, w = t >> 6;
    const int l31 = lane & 31, l5 = lane >> 5;
    const int m0 = blockIdx.x * 128, n0 = blockIdx.y * 96;
    const int arow = t >> 1, acol = (t & 1) * 16;   // A tile: 128 x 32
    const int wrow = t >> 1, wcol = (t & 1) * 16;   // W tile:  96 x 32 (t<192)

    f32x16 acc[3] = {};
    s16x8 rA0, rA1, rL0, rL1, rW0, rW1;

    auto LOAD = [&](int k0) {
        const size_t ab = (size_t)(m0 + arow) * KD + k0 + acol;
        rA0 = *reinterpret_cast<const s16x8*>(&Ah[ab]);
        rA1 = *reinterpret_cast<const s16x8*>(&Ah[ab + 8]);
        if constexpr (NT == 2) {
            rL0 = *reinterpret_cast<const s16x8*>(&Al[ab]);
            rL1 = *reinterpret_cast<const s16x8*>(&Al[ab + 8]);
        }
        if (t < 192) {
            const size_t wb = (size_t)(n0 + wrow) * KD + k0 + wcol;
            rW0 = *reinterpret_cast<const s16x8*>(&Wh[wb]);
            rW1 = *reinterpret_cast<const s16x8*>(&Wh[wb + 8]);
        }
    };
    auto STORE = [&]() {
        *reinterpret_cast<s16x8*>(&Ahs[arow][acol])     = rA0;
        *reinterpret_cast<s16x8*>(&Ahs[arow][acol + 8]) = rA1;
        if constexpr (NT == 2) {
            *reinterpret_cast<s16x8*>(&Als[arow][acol])     = rL0;
            *reinterpret_cast<s16x8*>(&Als[arow][acol + 8]) = rL1;
        }
        if (t < 192) {
            *reinterpret_cast<s16x8*>(&Whs[wrow][wcol])     = rW0;
            *reinterpret_cast<s16x8*>(&Whs[wrow][wcol + 8]) = rW1;
        }
    };

    LOAD(0); STORE();
    __syncthreads();

    for (int k0 = 0; k0 < KD; k0 += 32) {
        if (k0 + 32 < KD) LOAD(k0 + 32);
        #pragma unroll
        for (int ks = 0; ks < 2; ++ks) {
            const int koff = ks * 16 + l5 * 8;
            const f16x8 af = *reinterpret_cast<const f16x8*>(&Ahs[w * 32 + l31][koff]);
            f16x8 al;
            if constexpr (NT == 2)
                al = *reinterpret_cast<const f16x8*>(&Als[w * 32 + l31][koff]);
            #pragma unroll
            for (int nt = 0; nt < 3; ++nt) {
                const f16x8 wf = *reinterpret_cast<const f16x8*>(&Whs[nt * 32 + l31][koff]);
                acc[nt] = MFMA16(af, wf, acc[nt]);
                if constexpr (NT == 2) acc[nt] = MFMA16(al, wf, acc[nt]);
            }
        }
        __syncthreads();
        if (k0 + 32 < KD) STORE();
        __syncthreads();
    }

    #pragma unroll
    for (int nt = 0; nt < 3; ++nt) {
        const int n = n0 + nt * 32 + l31;
        const float bb = bias[n];
        #pragma unroll
        for (int reg = 0; reg < 16; ++reg) {
            const int rowl = (reg & 3) + 8 * (reg >> 2) + 4 * l5;
            const int m = m0 + w * 32 + rowl;
            float v = acc[nt][reg] + bb;
            if constexpr (QS) v *= LOG2E;
            if constexpr (EPI == 0) {
                const _Float16 h = (_Float16)v;
                ((ushort_t*)out0)[(size_t)m * 768 + n] = h_bits(h);
                ((ushort_t*)out1)[(size_t)m * 768 + n] =
                    h_bits((_Float16)(v - (float)h));
            } else if constexpr (EPI == 1) {
                const int hh = n >> 6, dh = n & 63, bq = m >> 11, lq = m & 2047;
                ((ushort_t*)out0)[((((size_t)bq * H + hh) * DH + dh) << 11) + lq] =
                    h_bits((_Float16)v);
            } else if constexpr (EPI == 2) {
                ((float*)out0)[(size_t)m * 768 + n] = v;
            } else {
                ((ushort_t*)out0)[(size_t)m * 768 + n] = h_bits((_Float16)v);
            }
        }
    }
}

// ---------------------------------------------------------------------------
// Flash attention, f16 MFMA 32x32x16, swapped QK^T (S^T = K*Q^T), 2-term.
// Grid (L/128, H, B); 4 waves; wave owns 32 q rows. P kept in registers
// via v_cvt_pkrtz + v_permlane32_swap. Defer-max (log2 domain, THR=12).
// Q pre-scaled by LOG2E (in projection epilogue) -> exp2 directly.
// ---------------------------------------------------------------------------
__global__ __launch_bounds__(256) void attn2(
    const ushort_t* __restrict__ qh, const ushort_t* __restrict__ ql,
    const ushort_t* __restrict__ kh, const ushort_t* __restrict__ vt,
    ushort_t* __restrict__ pf)
{
    __shared__ __align__(16) ushort_t Khs[64][72];
    __shared__ __align__(16) ushort_t Vts[64][72];
    __shared__ __align__(16) float scale_s[4][32];
    __shared__ __align__(16) float l_s[4][32];

    const int t = threadIdx.x, lane = t & 63, w = t >> 6;
    const int l31 = lane & 31, l5 = lane >> 5;
    const int qt = blockIdx.x, h = blockIdx.y, b = blockIdx.z;

    // Q fragments (B-operand: col=q=l31, k=d); hi and lo f16
    const int qrow = qt * 128 + w * 32 + l31;
    const size_t qb = ((size_t)(b * L + qrow)) * 768 + h * 64;
    f16x8 qfh[4], qfl[4];
    #pragma unroll
    for (int ks = 0; ks < 4; ++ks) {
        const int d = ks * 16 + l5 * 8;
        qfh[ks] = *reinterpret_cast<const f16x8*>(&qh[qb + d]);
        qfl[ks] = *reinterpret_cast<const f16x8*>(&ql[qb + d]);
    }

    f32x16 o[2] = {};
    float m_run = -3.0e38f, l_run = 0.0f;
    const int sr = t >> 3, scc = (t & 7) * 8;
    s16x8 rK0, rK1, rV0, rV1;

    auto LOADT = [&](int kt) {
        const size_t kg = ((size_t)(b * L + kt * 64 + sr)) * 768 + h * 64 + scc;
        rK0 = *reinterpret_cast<const s16x8*>(&kh[kg]);
        rK1 = *reinterpret_cast<const s16x8*>(&kh[kg + (size_t)32 * 768]);
        const size_t vg = (((size_t)b * H + h) * DH + sr) * (size_t)L + kt * 64 + scc;
        rV0 = *reinterpret_cast<const s16x8*>(&vt[vg]);
        rV1 = *reinterpret_cast<const s16x8*>(&vt[vg + (size_t)32 * L]);
    };
    auto STORET = [&]() {
        *reinterpret_cast<s16x8*>(&Khs[sr][scc])      = rK0;
        *reinterpret_cast<s16x8*>(&Khs[sr + 32][scc]) = rK1;
        *reinterpret_cast<s16x8*>(&Vts[sr][scc])      = rV0;
        *reinterpret_cast<s16x8*>(&Vts[sr + 32][scc]) = rV1;
    };

    LOADT(0); STORET();
    __syncthreads();

    for (int kt = 0; kt < L / 64; ++kt) {
        if (kt + 1 < L / 64) LOADT(kt + 1);

        // S^T = K * Q^T (2-term: K-hi x (Q-hi, Q-lo))
        f32x16 st[2] = {};
        #pragma unroll
        for (int mt = 0; mt < 2; ++mt) {
            #pragma unroll
            for (int ks = 0; ks < 4; ++ks) {
                const int koff = ks * 16 + l5 * 8;
                const f16x8 kf =
                    *reinterpret_cast<const f16x8*>(&Khs[mt * 32 + l31][koff]);
                st[mt] = MFMA16(kf, qfh[ks], st[mt]);
                st[mt] = MFMA16(kf, qfl[ks], st[mt]);
            }
        }

        // online softmax in log2 domain; lane owns q=l31
        float pmax = -3.0e38f;
        #pragma unroll
        for (int mt = 0; mt < 2; ++mt)
            #pragma unroll
            for (int e = 0; e < 16; ++e) pmax = fmaxf(pmax, st[mt][e]);
        pmax = fmaxf(pmax, __shfl_xor(pmax, 32));

        if (!__all(pmax - m_run <= 12.0f)) {      // defer-max: rescale rarely
            const float mnew = fmaxf(m_run, pmax);
            const float sc = EXP2(m_run - mnew);
            m_run = mnew;
            l_run *= sc;
            scale_s[w][l31] = sc;                 // wave-local bounce to rows
            #pragma unroll
            for (int rg = 0; rg < 4; ++rg) {
                const f32x4 sc4 =
                    *reinterpret_cast<const f32x4*>(&scale_s[w][8 * rg + 4 * l5]);
                #pragma unroll
                for (int j = 0; j < 4; ++j) {
                    o[0][rg * 4 + j] *= sc4[j];
                    o[1][rg * 4 + j] *= sc4[j];
                }
            }
        }

        float sum = 0.0f;
        #pragma unroll
        for (int mt = 0; mt < 2; ++mt)
            #pragma unroll
            for (int e = 0; e < 16; ++e) {
                const float p = EXP2(st[mt][e] - m_run);
                st[mt][e] = p;
                sum += p;
            }
        sum += __shfl_xor(sum, 32);
        l_run += sum;

        // pack P -> PV A-operand fragments in registers (cvt_pkrtz + permlane).
        // plswap(x,y): x={x_lo,y_lo}, y={x_hi,y_hi} (dst_hi <-> src_lo).
        f16x8 pa[4];
        #pragma unroll
        for (int mt = 0; mt < 2; ++mt) {
            #pragma unroll
            for (int hf = 0; hf < 2; ++hf) {
                uint_t a0 = pkrtz(st[mt][8 * hf + 0], st[mt][8 * hf + 1]);
                uint_t a1 = pkrtz(st[mt][8 * hf + 2], st[mt][8 * hf + 3]);
                uint_t b0 = pkrtz(st[mt][8 * hf + 4], st[mt][8 * hf + 5]);
                uint_t b1 = pkrtz(st[mt][8 * hf + 6], st[mt][8 * hf + 7]);
                plswap(a0, b0);   // a0 -> word0 {keys l5*8+0,1}, b0 -> word2 {+4,5}
                plswap(a1, b1);   // a1 -> word1 {keys l5*8+2,3}, b1 -> word3 {+6,7}
                u32x4 pk4; pk4[0] = a0; pk4[1] = a1; pk4[2] = b0; pk4[3] = b1;
                pa[mt * 2 + hf] = __builtin_bit_cast(f16x8, pk4);
            }
        }

        // O += P * V
        #pragma unroll
        for (int ks = 0; ks < 4; ++ks) {
            const int koff = ks * 16 + l5 * 8;
            #pragma unroll
            for (int dt = 0; dt < 2; ++dt) {
                const f16x8 vb =
                    *reinterpret_cast<const f16x8*>(&Vts[dt * 32 + l31][koff]);
                o[dt] = MFMA16(pa[ks], vb, o[dt]);
            }
        }

        __syncthreads();                 // all waves done reading K/V tiles
        if (kt + 1 < L / 64) STORET();   // overwrite with prefetched tile
        __syncthreads();
    }

    l_s[w][l31] = l_run;                 // wave-local bounce to rows
    const size_t ob = ((size_t)(b * L + qt * 128 + w * 32)) * 768 + h * 64;
    #pragma unroll
    for (int rg = 0; rg < 4; ++rg) {
        const f32x4 lv = *reinterpret_cast<const f32x4*>(&l_s[w][8 * rg + 4 * l5]);
        #pragma unroll
        for (int j = 0; j < 4; ++j) {
            const float inv = 1.0f / lv[j];
            const int rowl = j + 8 * rg + 4 * l5;
            #pragma unroll
            for (int dt = 0; dt < 2; ++dt) {
                pf[ob + (size_t)rowl * 768 + dt * 32 + l31] =
                    h_bits((_Float16)(o[dt][rg * 4 + j] * inv));
            }
        }
    }
}

// ---------------------------------------------------------------------------
extern "C" void kernel_launch(void* const* d_in, const int* in_sizes, int n_in,
                              void* d_out, int out_size, void* d_ws, size_t ws_size,
                              hipStream_t stream)
{
    const float* x  = (const float*)d_in[0];
    const float* Wq = (const float*)d_in[1];
    const float* bq = (const float*)d_in[2];
    const float* Wk = (const float*)d_in[3];
    const float* bk = (const float*)d_in[4];
    const float* Wv = (const float*)d_in[5];
    const float* bv = (const float*)d_in[6];
    const float* Wd = (const float*)d_in[7];
    const float* bd = (const float*)d_in[8];
    float* out = (float*)d_out;

    constexpr size_t S  = (size_t)M * 768;   // activation slab (elements)
    constexpr size_t WS = (size_t)768 * 768; // weight slab (elements)
    ushort_t* p = (ushort_t*)d_ws;
    ushort_t* xh  = p; p += S;
    ushort_t* xl  = p; p += S;
    ushort_t* qhb = p; p += S;
    ushort_t* qlb = p; p += S;
    ushort_t* khb = p; p += S;
    ushort_t* vtb = p; p += S;
    ushort_t* WqT = p; p += WS;
    ushort_t* WkT = p; p += WS;
    ushort_t* WvT = p; p += WS;
    ushort_t* WdT = p; p += WS;
    ushort_t* pfb = xl;                      // xl dead after K projection

    // preps
    split_x<<<dim3((int)(S / 1024)), dim3(256), 0, stream>>>(x, xh, xl, (int)S);
    h16T_w<<<dim3(576), dim3(256), 0, stream>>>(Wq, WqT);
    h16T_w<<<dim3(576), dim3(256), 0, stream>>>(Wk, WkT);
    h16T_w<<<dim3(576), dim3(256), 0, stream>>>(Wv, WvT);
    h16T_w<<<dim3(576), dim3(256), 0, stream>>>(Wd, WdT);

    const dim3 gg(M / 128, DM / 96);         // (64, 8)
    const dim3 blk(256);

    // Q: 2-term, split hi/lo out, scaled by LOG2E.  K: 2-term, f16 out.
    gemm2<2, 0, 1><<<gg, blk, 0, stream>>>(xh, xl, WqT, bq, qhb, qlb);
    gemm2<2, 3, 0><<<gg, blk, 0, stream>>>(xh, xl, WkT, bk, khb, nullptr);
    // V: 1-term, transposed f16 out.
    gemm2<1, 1, 0><<<gg, blk, 0, stream>>>(xh, nullptr, WvT, bv, vtb, nullptr);

    // attention
    attn2<<<dim3(L / 128, H, B), blk, 0, stream>>>(qhb, qlb, khb, vtb, pfb);

    // output projection: prefinal f16 x WdT -> fp32 out
    gemm2<1, 2, 0><<<gg, blk, 0, stream>>>(pfb, nullptr, WdT, bd, out, nullptr);
}

// Round 8
// 252.373 us; speedup vs baseline: 7.8657x; 1.2405x over previous
//
#include <hip/hip_runtime.h>
#include <math.h>

// (B,L,DM,H,DH) = (4,2048,768,12,64)
constexpr int B  = 4;
constexpr int L  = 2048;
constexpr int DM = 768;
constexpr int H  = 12;
constexpr int DH = 64;
constexpr int M  = B * L;          // 8192
constexpr float LOG2E = 1.4426950408889634f;

typedef __attribute__((ext_vector_type(8)))  _Float16       f16x8;
typedef __attribute__((ext_vector_type(8)))  short          s16x8;
typedef __attribute__((ext_vector_type(4)))  unsigned short u16x4;
typedef __attribute__((ext_vector_type(8)))  unsigned short u16x8;
typedef __attribute__((ext_vector_type(4)))  unsigned int   u32x4;
typedef __attribute__((ext_vector_type(16))) float          f32x16;
typedef __attribute__((ext_vector_type(4)))  float          f32x4;
typedef unsigned short ushort_t;
typedef unsigned int   uint_t;

#define MFMA16(a, b, c) __builtin_amdgcn_mfma_f32_32x32x16_f16((a), (b), (c), 0, 0, 0)

#if __has_builtin(__builtin_amdgcn_exp2f)
#define EXP2(x) __builtin_amdgcn_exp2f(x)
#else
#define EXP2(x) exp2f(x)
#endif

__device__ __forceinline__ ushort_t h_bits(_Float16 h) {
    return __builtin_bit_cast(ushort_t, h);
}
__device__ __forceinline__ uint_t pkrtz(float a, float b) {
    return __builtin_bit_cast(uint_t, __builtin_amdgcn_cvt_pkrtz(a, b));
}
__device__ __forceinline__ void plswap(uint_t& x, uint_t& y) {
    // v_permlane32_swap_b32 vdst, vsrc: exchanges vdst lanes[32:63] with
    // vsrc lanes[0:31]. After plswap(x,y): x = {x_lo, y_lo}, y = {x_hi, y_hi}.
    asm volatile("v_permlane32_swap_b32 %0, %1" : "+v"(x), "+v"(y));
}

// ---------------------------------------------------------------------------
// Prep: cast x (fp32) -> f16
// ---------------------------------------------------------------------------
__global__ __launch_bounds__(256) void cast_x(
    const float* __restrict__ x, ushort_t* __restrict__ xh, int n)
{
    const int i = (blockIdx.x * 256 + threadIdx.x) * 4;
    if (i >= n) return;
    const float4 v = *reinterpret_cast<const float4*>(&x[i]);
    u16x4 hh;
    hh[0] = h_bits((_Float16)v.x); hh[1] = h_bits((_Float16)v.y);
    hh[2] = h_bits((_Float16)v.z); hh[3] = h_bits((_Float16)v.w);
    *reinterpret_cast<u16x4*>(&xh[i]) = hh;
}

// ---------------------------------------------------------------------------
// Prep: all 4 weights [768x768] fp32 -> transposed f16 WT[n][k], one launch.
// Grid (12,12,4); block 256. 64x64 tile via LDS (both sides coalesced).
// ---------------------------------------------------------------------------
__global__ __launch_bounds__(256) void wtransAll(
    const float* __restrict__ W0, const float* __restrict__ W1,
    const float* __restrict__ W2, const float* __restrict__ W3,
    ushort_t* __restrict__ T0, ushort_t* __restrict__ T1,
    ushort_t* __restrict__ T2, ushort_t* __restrict__ T3)
{
    __shared__ ushort_t Tls[64][72];   // [n][k], pad 8
    const int t = threadIdx.x;
    const int k0 = blockIdx.x * 64, n0 = blockIdx.y * 64, wsel = blockIdx.z;
    const float* W = wsel == 0 ? W0 : wsel == 1 ? W1 : wsel == 2 ? W2 : W3;
    ushort_t*    T = wsel == 0 ? T0 : wsel == 1 ? T1 : wsel == 2 ? T2 : T3;

    #pragma unroll
    for (int it = 0; it < 4; ++it) {            // load 16 rows (k) per iter
        const int idx = it * 256 + t;
        const int r = idx >> 4, c = (idx & 15) * 4;    // r=k-local, c=n-local
        const float4 v = *reinterpret_cast<const float4*>(
            &W[(size_t)(k0 + r) * 768 + n0 + c]);
        Tls[c + 0][r] = h_bits((_Float16)v.x);
        Tls[c + 1][r] = h_bits((_Float16)v.y);
        Tls[c + 2][r] = h_bits((_Float16)v.z);
        Tls[c + 3][r] = h_bits((_Float16)v.w);
    }
    __syncthreads();
    #pragma unroll
    for (int it = 0; it < 4; ++it) {            // write 16 rows (n) per iter
        const int idx = it * 256 + t;
        const int r = idx >> 4, c = (idx & 15) * 4;    // r=n-local, c=k-local
        *reinterpret_cast<u16x4*>(&T[(size_t)(n0 + r) * 768 + k0 + c]) =
            *reinterpret_cast<const u16x4*>(&Tls[r][c]);
    }
}

// ---------------------------------------------------------------------------
// MFMA GEMM: C[M,768] = A[M,768]*W[768,768] + bias, f16 32x32x16, 1-term.
// Tile 128x96, 4 waves (each 32 rows x 96 cols), BK=32, reg-prefetch.
// EPI 1: f16 transposed -> vt[b][h][dh][l], coalesced via LDS bounce (V)
// EPI 2: fp32           -> out0            (final)
// EPI 3: f16 plain      -> out0            (Q with LOG2E if QS, K)
// ---------------------------------------------------------------------------
template<int EPI, int QS>
__global__ __launch_bounds__(256) void gemm2(
    const ushort_t* __restrict__ Ah, const ushort_t* __restrict__ Wh,
    const float* __restrict__ bias, void* __restrict__ out0)
{
    constexpr int KD = 768;
    __shared__ __align__(16) ushort_t Ahs[128][40];
    __shared__ __align__(16) ushort_t Whs[96][40];
    __shared__ __align__(16) ushort_t Ots[EPI == 1 ? 96 : 1][EPI == 1 ? 136 : 8];

    const int t = threadIdx.x, lane = t & 63, w = t >> 6;
    const int l31 = lane & 31, l5 = lane >> 5;
    const int m0 = blockIdx.x * 128, n0 = blockIdx.y * 96;
    const int arow = t >> 1, acol = (t & 1) * 16;   // A tile: 128 x 32
    const int wrow = t >> 1, wcol = (t & 1) * 16;   // W tile:  96 x 32 (t<192)

    f32x16 acc[3] = {};
    s16x8 rA0, rA1, rW0, rW1;

    auto LOAD = [&](int k0) {
        const size_t ab = (size_t)(m0 + arow) * KD + k0 + acol;
        rA0 = *reinterpret_cast<const s16x8*>(&Ah[ab]);
        rA1 = *reinterpret_cast<const s16x8*>(&Ah[ab + 8]);
        if (t < 192) {
            const size_t wb = (size_t)(n0 + wrow) * KD + k0 + wcol;
            rW0 = *reinterpret_cast<const s16x8*>(&Wh[wb]);
            rW1 = *reinterpret_cast<const s16x8*>(&Wh[wb + 8]);
        }
    };
    auto STORE = [&]() {
        *reinterpret_cast<s16x8*>(&Ahs[arow][acol])     = rA0;
        *reinterpret_cast<s16x8*>(&Ahs[arow][acol + 8]) = rA1;
        if (t < 192) {
            *reinterpret_cast<s16x8*>(&Whs[wrow][wcol])     = rW0;
            *reinterpret_cast<s16x8*>(&Whs[wrow][wcol + 8]) = rW1;
        }
    };

    LOAD(0); STORE();
    __syncthreads();

    for (int k0 = 0; k0 < KD; k0 += 32) {
        if (k0 + 32 < KD) LOAD(k0 + 32);
        #pragma unroll
        for (int ks = 0; ks < 2; ++ks) {
            const int koff = ks * 16 + l5 * 8;
            const f16x8 af = *reinterpret_cast<const f16x8*>(&Ahs[w * 32 + l31][koff]);
            #pragma unroll
            for (int nt = 0; nt < 3; ++nt) {
                const f16x8 wf = *reinterpret_cast<const f16x8*>(&Whs[nt * 32 + l31][koff]);
                acc[nt] = MFMA16(af, wf, acc[nt]);
            }
        }
        __syncthreads();
        if (k0 + 32 < KD) STORE();
        __syncthreads();
    }

    if constexpr (EPI == 1) {
        // V: bounce through LDS, write coalesced rows of vt[b][h][dh][:].
        #pragma unroll
        for (int nt = 0; nt < 3; ++nt) {
            const float bb = bias[n0 + nt * 32 + l31];
            #pragma unroll
            for (int reg = 0; reg < 16; ++reg) {
                const int rowl = (reg & 3) + 8 * (reg >> 2) + 4 * l5;
                Ots[nt * 32 + l31][w * 32 + rowl] =
                    h_bits((_Float16)(acc[nt][reg] + bb));
            }
        }
        __syncthreads();
        ushort_t* vt = (ushort_t*)out0;
        const int bq = m0 >> 11, lq = m0 & 2047;
        #pragma unroll
        for (int it = 0; it < 6; ++it) {        // 96 rows x 16 chunks / 256
            const int idx = it * 256 + t;
            const int r = idx >> 4, c = (idx & 15) * 8;
            const int n = n0 + r, hh = n >> 6, dh = n & 63;
            *reinterpret_cast<u16x8*>(
                &vt[((((size_t)bq * H + hh) * DH + dh) << 11) + lq + c]) =
                *reinterpret_cast<const u16x8*>(&Ots[r][c]);
        }
    } else {
        #pragma unroll
        for (int nt = 0; nt < 3; ++nt) {
            const int n = n0 + nt * 32 + l31;
            const float bb = bias[n];
            #pragma unroll
            for (int reg = 0; reg < 16; ++reg) {
                const int rowl = (reg & 3) + 8 * (reg >> 2) + 4 * l5;
                const int m = m0 + w * 32 + rowl;
                float v = acc[nt][reg] + bb;
                if constexpr (QS) v *= LOG2E;
                if constexpr (EPI == 2) {
                    ((float*)out0)[(size_t)m * 768 + n] = v;
                } else {
                    ((ushort_t*)out0)[(size_t)m * 768 + n] = h_bits((_Float16)v);
                }
            }
        }
    }
}

// ---------------------------------------------------------------------------
// Flash attention, f16 MFMA 32x32x16, swapped QK^T (S^T = K*Q^T), 1-term.
// Grid (L/128, H, B); 4 waves; wave owns 32 q rows. P kept in registers
// via v_cvt_pkrtz + v_permlane32_swap. Defer-max (log2 domain, THR=12).
// Q pre-scaled by LOG2E (in projection epilogue) -> exp2 directly.
// ---------------------------------------------------------------------------
__global__ __launch_bounds__(256) void attn2(
    const ushort_t* __restrict__ qh, const ushort_t* __restrict__ kh,
    const ushort_t* __restrict__ vt, ushort_t* __restrict__ pf)
{
    __shared__ __align__(16) ushort_t Khs[64][72];
    __shared__ __align__(16) ushort_t Vts[64][72];
    __shared__ __align__(16) float scale_s[4][32];
    __shared__ __align__(16) float l_s[4][32];

    const int t = threadIdx.x, lane = t & 63, w = t >> 6;
    const int l31 = lane & 31, l5 = lane >> 5;
    const int qt = blockIdx.x, h = blockIdx.y, b = blockIdx.z;

    // Q fragments (B-operand: col=q=l31, k=d)
    const int qrow = qt * 128 + w * 32 + l31;
    const size_t qb = ((size_t)(b * L + qrow)) * 768 + h * 64;
    f16x8 qfh[4];
    #pragma unroll
    for (int ks = 0; ks < 4; ++ks)
        qfh[ks] = *reinterpret_cast<const f16x8*>(&qh[qb + ks * 16 + l5 * 8]);

    f32x16 o[2] = {};
    float m_run = -3.0e38f, l_run = 0.0f;
    const int sr = t >> 3, scc = (t & 7) * 8;
    s16x8 rK0, rK1, rV0, rV1;

    auto LOADT = [&](int kt) {
        const size_t kg = ((size_t)(b * L + kt * 64 + sr)) * 768 + h * 64 + scc;
        rK0 = *reinterpret_cast<const s16x8*>(&kh[kg]);
        rK1 = *reinterpret_cast<const s16x8*>(&kh[kg + (size_t)32 * 768]);
        const size_t vg = (((size_t)b * H + h) * DH + sr) * (size_t)L + kt * 64 + scc;
        rV0 = *reinterpret_cast<const s16x8*>(&vt[vg]);
        rV1 = *reinterpret_cast<const s16x8*>(&vt[vg + (size_t)32 * L]);
    };
    auto STORET = [&]() {
        *reinterpret_cast<s16x8*>(&Khs[sr][scc])      = rK0;
        *reinterpret_cast<s16x8*>(&Khs[sr + 32][scc]) = rK1;
        *reinterpret_cast<s16x8*>(&Vts[sr][scc])      = rV0;
        *reinterpret_cast<s16x8*>(&Vts[sr + 32][scc]) = rV1;
    };

    LOADT(0); STORET();
    __syncthreads();

    for (int kt = 0; kt < L / 64; ++kt) {
        if (kt + 1 < L / 64) LOADT(kt + 1);

        // S^T = K * Q^T (1-term f16)
        f32x16 st[2] = {};
        #pragma unroll
        for (int mt = 0; mt < 2; ++mt) {
            #pragma unroll
            for (int ks = 0; ks < 4; ++ks) {
                const f16x8 kf = *reinterpret_cast<const f16x8*>(
                    &Khs[mt * 32 + l31][ks * 16 + l5 * 8]);
                st[mt] = MFMA16(kf, qfh[ks], st[mt]);
            }
        }

        // online softmax in log2 domain; lane owns q=l31
        float pmax = -3.0e38f;
        #pragma unroll
        for (int mt = 0; mt < 2; ++mt)
            #pragma unroll
            for (int e = 0; e < 16; ++e) pmax = fmaxf(pmax, st[mt][e]);
        pmax = fmaxf(pmax, __shfl_xor(pmax, 32));

        if (!__all(pmax - m_run <= 12.0f)) {      // defer-max: rescale rarely
            const float mnew = fmaxf(m_run, pmax);
            const float sc = EXP2(m_run - mnew);
            m_run = mnew;
            l_run *= sc;
            scale_s[w][l31] = sc;                 // wave-local bounce to rows
            #pragma unroll
            for (int rg = 0; rg < 4; ++rg) {
                const f32x4 sc4 =
                    *reinterpret_cast<const f32x4*>(&scale_s[w][8 * rg + 4 * l5]);
                #pragma unroll
                for (int j = 0; j < 4; ++j) {
                    o[0][rg * 4 + j] *= sc4[j];
                    o[1][rg * 4 + j] *= sc4[j];
                }
            }
        }

        float sum = 0.0f;
        #pragma unroll
        for (int mt = 0; mt < 2; ++mt)
            #pragma unroll
            for (int e = 0; e < 16; ++e) {
                const float p = EXP2(st[mt][e] - m_run);
                st[mt][e] = p;
                sum += p;
            }
        sum += __shfl_xor(sum, 32);
        l_run += sum;

        // pack P -> PV A-operand fragments in registers (cvt_pkrtz + permlane).
        // plswap(x,y): x={x_lo,y_lo}, y={x_hi,y_hi} (dst_hi <-> src_lo).
        f16x8 pa[4];
        #pragma unroll
        for (int mt = 0; mt < 2; ++mt) {
            #pragma unroll
            for (int hf = 0; hf < 2; ++hf) {
                uint_t a0 = pkrtz(st[mt][8 * hf + 0], st[mt][8 * hf + 1]);
                uint_t a1 = pkrtz(st[mt][8 * hf + 2], st[mt][8 * hf + 3]);
                uint_t b0 = pkrtz(st[mt][8 * hf + 4], st[mt][8 * hf + 5]);
                uint_t b1 = pkrtz(st[mt][8 * hf + 6], st[mt][8 * hf + 7]);
                plswap(a0, b0);   // a0 -> word0 {keys l5*8+0,1}, b0 -> word2 {+4,5}
                plswap(a1, b1);   // a1 -> word1 {keys l5*8+2,3}, b1 -> word3 {+6,7}
                u32x4 pk4; pk4[0] = a0; pk4[1] = a1; pk4[2] = b0; pk4[3] = b1;
                pa[mt * 2 + hf] = __builtin_bit_cast(f16x8, pk4);
            }
        }

        // O += P * V
        #pragma unroll
        for (int ks = 0; ks < 4; ++ks) {
            const int koff = ks * 16 + l5 * 8;
            #pragma unroll
            for (int dt = 0; dt < 2; ++dt) {
                const f16x8 vb =
                    *reinterpret_cast<const f16x8*>(&Vts[dt * 32 + l31][koff]);
                o[dt] = MFMA16(pa[ks], vb, o[dt]);
            }
        }

        __syncthreads();                 // all waves done reading K/V tiles
        if (kt + 1 < L / 64) STORET();   // overwrite with prefetched tile
        __syncthreads();
    }

    l_s[w][l31] = l_run;                 // wave-local bounce to rows
    const size_t ob = ((size_t)(b * L + qt * 128 + w * 32)) * 768 + h * 64;
    #pragma unroll
    for (int rg = 0; rg < 4; ++rg) {
        const f32x4 lv = *reinterpret_cast<const f32x4*>(&l_s[w][8 * rg + 4 * l5]);
        #pragma unroll
        for (int j = 0; j < 4; ++j) {
            const float inv = 1.0f / lv[j];
            const int rowl = j + 8 * rg + 4 * l5;
            #pragma unroll
            for (int dt = 0; dt < 2; ++dt) {
                pf[ob + (size_t)rowl * 768 + dt * 32 + l31] =
                    h_bits((_Float16)(o[dt][rg * 4 + j] * inv));
            }
        }
    }
}

// ---------------------------------------------------------------------------
extern "C" void kernel_launch(void* const* d_in, const int* in_sizes, int n_in,
                              void* d_out, int out_size, void* d_ws, size_t ws_size,
                              hipStream_t stream)
{
    const float* x  = (const float*)d_in[0];
    const float* Wq = (const float*)d_in[1];
    const float* bq = (const float*)d_in[2];
    const float* Wk = (const float*)d_in[3];
    const float* bk = (const float*)d_in[4];
    const float* Wv = (const float*)d_in[5];
    const float* bv = (const float*)d_in[6];
    const float* Wd = (const float*)d_in[7];
    const float* bd = (const float*)d_in[8];
    float* out = (float*)d_out;

    constexpr size_t S  = (size_t)M * 768;   // activation slab (elements)
    constexpr size_t WS = (size_t)768 * 768; // weight slab (elements)
    ushort_t* p = (ushort_t*)d_ws;
    ushort_t* xh  = p; p += S;
    ushort_t* qhb = p; p += S;
    ushort_t* khb = p; p += S;
    ushort_t* vtb = p; p += S;
    ushort_t* WqT = p; p += WS;
    ushort_t* WkT = p; p += WS;
    ushort_t* WvT = p; p += WS;
    ushort_t* WdT = p; p += WS;
    ushort_t* pfb = xh;                      // xh dead after V projection

    // preps
    cast_x<<<dim3((int)(S / 1024)), dim3(256), 0, stream>>>(x, xh, (int)S);
    wtransAll<<<dim3(12, 12, 4), dim3(256), 0, stream>>>(
        Wq, Wk, Wv, Wd, WqT, WkT, WvT, WdT);

    const dim3 gg(M / 128, DM / 96);         // (64, 8)
    const dim3 blk(256);

    // Q: f16 out scaled by LOG2E.  K: f16 out.  V: transposed f16 out.
    gemm2<3, 1><<<gg, blk, 0, stream>>>(xh, WqT, bq, qhb);
    gemm2<3, 0><<<gg, blk, 0, stream>>>(xh, WkT, bk, khb);
    gemm2<1, 0><<<gg, blk, 0, stream>>>(xh, WvT, bv, vtb);

    // attention
    attn2<<<dim3(L / 128, H, B), blk, 0, stream>>>(qhb, khb, vtb, pfb);

    // output projection: prefinal f16 x WdT -> fp32 out
    gemm2<2, 0><<<gg, blk, 0, stream>>>(pfb, WdT, bd, out);
}